// Round 3
// baseline (642.058 us; speedup 1.0000x reference)
//
#include <hip/hip_runtime.h>

typedef unsigned short u16;
typedef short bfrag __attribute__((ext_vector_type(8)));   // 8 bf16 (4 VGPRs)
typedef float facc  __attribute__((ext_vector_type(4)));   // 4 fp32 acc

#define LOG2E 1.44269504088896340736f

static __device__ __forceinline__ float bf2f(u16 b) {
  union { unsigned u; float f; } v; v.u = ((unsigned)b) << 16; return v.f;
}
static __device__ __forceinline__ u16 f2bf(float x) {  // RNE
  union { float f; unsigned u; } v; v.f = x;
  return (u16)((v.u + 0x7FFFu + ((v.u >> 16) & 1u)) >> 16);
}
static __device__ __forceinline__ void gload_lds16(const u16* g, u16* l) {
  __builtin_amdgcn_global_load_lds((const __attribute__((address_space(1))) void*)g,
                                   (__attribute__((address_space(3))) void*)l,
                                   16, 0, 0);
}

// Kernel 0: f32 -> bf16 RNE pre-convert of x, qkv_w, proj_w (memory-bound, ~48MB)
__global__ __launch_bounds__(256) void convert_kernel(
    const float* __restrict__ x, const float* __restrict__ qw, const float* __restrict__ pw,
    u16* __restrict__ xb, u16* __restrict__ qwb, u16* __restrict__ pwb)
{
  const int NX = 4 * 1024 * 1024, NQ = 3 * 1024 * 1024, NP = 1024 * 1024;
  const int total4 = (NX + NQ + NP) >> 2;
  for (int i = blockIdx.x * blockDim.x + threadIdx.x; i < total4;
       i += gridDim.x * blockDim.x) {
    const int e = i << 2;
    const float* s; u16* d; int off;
    if (e < NX)            { s = x;  d = xb;  off = e; }
    else if (e < NX + NQ)  { s = qw; d = qwb; off = e - NX; }
    else                   { s = pw; d = pwb; off = e - NX - NQ; }
    float4 v = *(const float4*)(s + off);
    ushort4 o;
    o.x = f2bf(v.x); o.y = f2bf(v.y); o.z = f2bf(v.z); o.w = f2bf(v.w);
    *(ushort4*)(d + off) = o;
  }
}

// C[m][n] = sum_k A[m][k] * B[n][k]   (B^T GEMM, bf16). 128x128 tile / 256 thr.
static __device__ __forceinline__ void gemm128_bt(
    const u16* __restrict__ A, const u16* __restrict__ B, int K,
    int m0, int n0, u16* As, u16* Bs, facc acc[4][4])
{
  const int lane = threadIdx.x & 63;
  const int wv   = threadIdx.x >> 6;
  const int quad = lane >> 4;
  const int l15  = lane & 15;
  const int wm = wv >> 1, wn = wv & 1;
  const int srow = lane >> 2;        // 16 rows per wave-call
  const int skb  = (lane & 3) * 8;   // 4 x 8 bf16 = 64B per row

  facc zero = {0.f, 0.f, 0.f, 0.f};
#pragma unroll
  for (int i = 0; i < 4; ++i)
#pragma unroll
    for (int j = 0; j < 4; ++j) acc[i][j] = zero;

  const int nIter = K >> 5;
  for (int kk = 0; kk < nIter; ++kk) {
    const int k0 = kk << 5;
    __syncthreads();                  // previous compute done before LDS overwrite
#pragma unroll
    for (int c = 0; c < 2; ++c) {
      const int seg = wv * 2 + c;     // 8 segs x 16 rows = 128 rows
      gload_lds16(A + (long)(m0 + seg * 16 + srow) * K + k0 + skb, As + seg * 512);
      gload_lds16(B + (long)(n0 + seg * 16 + srow) * K + k0 + skb, Bs + seg * 512);
    }
    __syncthreads();                  // compiler drains vmcnt before barrier
    bfrag af[4], bf[4];
#pragma unroll
    for (int i = 0; i < 4; ++i)
      af[i] = *(const bfrag*)(As + (wm * 64 + i * 16 + l15) * 32 + quad * 8);
#pragma unroll
    for (int j = 0; j < 4; ++j)
      bf[j] = *(const bfrag*)(Bs + (wn * 64 + j * 16 + l15) * 32 + quad * 8);
#pragma unroll
    for (int i = 0; i < 4; ++i)
#pragma unroll
      for (int j = 0; j < 4; ++j)
        acc[i][j] = __builtin_amdgcn_mfma_f32_16x16x32_bf16(af[i], bf[j], acc[i][j], 0, 0, 0);
  }
}

// Kernel 1: qkv = x @ qkv_w^T + qkv_b.  Scatter: Q(scaled) [B,H,N,D], K [B,H,N,D],
// V transposed [B,H,D,N] so PV's B-operand is contiguous.
__global__ __launch_bounds__(256) void qkv_gemm_kernel(
    const u16* __restrict__ x, const u16* __restrict__ w,
    const float* __restrict__ qb, const float* __restrict__ vb,
    u16* __restrict__ Q, u16* __restrict__ Kd, u16* __restrict__ Vt)
{
  __shared__ u16 As[128 * 32];
  __shared__ u16 Bs[128 * 32];
  facc acc[4][4];
  const int m0 = blockIdx.y * 128;   // rows of x (B*N = 4096)
  const int n0 = blockIdx.x * 128;   // cols (3C = 3072)
  gemm128_bt(x, w, 1024, m0, n0, As, Bs, acc);

  const int lane = threadIdx.x & 63;
  const int wv = threadIdx.x >> 6;
  const int quad = lane >> 4, l15 = lane & 15;
  const int wm = wv >> 1, wn = wv & 1;
  const int ncb = n0 + wn * 64;        // wave-uniform: one (which, h) per wave
  const int which = ncb >> 10;         // 0=Q 1=K 2=V
  const int h = (ncb >> 6) & 15;

#pragma unroll
  for (int j = 0; j < 4; ++j) {
    const int d = j * 16 + l15;        // d within head
    const int n_g = ncb + d;
#pragma unroll
    for (int i = 0; i < 4; ++i) {
      const int mg0 = m0 + wm * 64 + i * 16 + quad * 4;   // 4-aligned
      const int b  = mg0 >> 11;
      const int ns = mg0 & 2047;
      if (which == 0) {
        const float qbv = qb[n_g];
#pragma unroll
        for (int r = 0; r < 4; ++r)
          Q[(((long)(b * 16 + h) * 2048 + ns + r) << 6) + d] =
              f2bf((acc[i][j][r] + qbv) * 0.125f);          // (x@W+qb)*SCALE
      } else if (which == 1) {
#pragma unroll
        for (int r = 0; r < 4; ++r)
          Kd[(((long)(b * 16 + h) * 2048 + ns + r) << 6) + d] = f2bf(acc[i][j][r]);
      } else {
        const float vbv = vb[n_g - 2048];
        ushort4 pk;                                          // 4 consecutive n -> 8B store
        pk.x = f2bf(acc[i][j][0] + vbv);
        pk.y = f2bf(acc[i][j][1] + vbv);
        pk.z = f2bf(acc[i][j][2] + vbv);
        pk.w = f2bf(acc[i][j][3] + vbv);
        *(ushort4*)(Vt + (((long)((b * 16 + h) * 64 + d)) << 11) + ns) = pk;
      }
    }
  }
}

// Kernel 2: flash attention. 1 block = (bh, 64 q-rows); 1 wave = 16 q-rows.
__global__ __launch_bounds__(256) void attn_kernel(
    const u16* __restrict__ Q, const u16* __restrict__ Kd, const u16* __restrict__ Vt,
    const float* __restrict__ bias, u16* __restrict__ AO)
{
  __shared__ u16 P[4][16 * 32];   // wave-private P tiles (16q x 32k bf16)
  const int lane = threadIdx.x & 63;
  const int wv = threadIdx.x >> 6;
  const int quad = lane >> 4, l15 = lane & 15;
  const int bh = blockIdx.x >> 5;
  const int qt = blockIdx.x & 31;
  const int h = bh & 15;
  const int b = bh >> 4;
  const int q0 = qt * 64 + wv * 16;
  const long baseN = (long)bh << 17;   // bh * 2048 * 64

  // Q A-frags for this wave's 16 rows (already scaled+biased)
  bfrag qf0 = *(const bfrag*)(Q + baseN + (long)(q0 + l15) * 64 + quad * 8);
  bfrag qf1 = *(const bfrag*)(Q + baseN + (long)(q0 + l15) * 64 + 32 + quad * 8);

  facc o[4];
  float m_i[4], l_i[4];
  facc zero = {0.f, 0.f, 0.f, 0.f};
#pragma unroll
  for (int t = 0; t < 4; ++t) o[t] = zero;
#pragma unroll
  for (int r = 0; r < 4; ++r) { m_i[r] = -1e30f; l_i[r] = 0.f; }

  const float* brow = bias + ((long)h << 22) + ((long)q0 << 11);
  u16* Pw = &P[wv][0];

  for (int k0 = 0; k0 < 2048; k0 += 32) {
    // S = Q K^T for 2 x (16q x 16k) tiles; K rows load as A-style frags = B^T operand
    facc s[2];
#pragma unroll
    for (int kt = 0; kt < 2; ++kt) {
      bfrag kf0 = *(const bfrag*)(Kd + baseN + (long)(k0 + kt * 16 + l15) * 64 + quad * 8);
      bfrag kf1 = *(const bfrag*)(Kd + baseN + (long)(k0 + kt * 16 + l15) * 64 + 32 + quad * 8);
      facc z = zero;
      z = __builtin_amdgcn_mfma_f32_16x16x32_bf16(qf0, kf0, z, 0, 0, 0);
      z = __builtin_amdgcn_mfma_f32_16x16x32_bf16(qf1, kf1, z, 0, 0, 0);
      s[kt] = z;
    }
    // + rel_pos_bias (f32 direct; C-layout: row=quad*4+r is q, col=l15 is key)
#pragma unroll
    for (int kt = 0; kt < 2; ++kt)
#pragma unroll
      for (int r = 0; r < 4; ++r)
        s[kt][r] += brow[(long)(quad * 4 + r) * 2048 + k0 + kt * 16 + l15];

    // online softmax: row reductions across the 16 lanes of the quad
    float alpha[4];
#pragma unroll
    for (int r = 0; r < 4; ++r) {
      float v = fmaxf(s[0][r], s[1][r]);
      v = fmaxf(v, __shfl_xor(v, 1, 16));
      v = fmaxf(v, __shfl_xor(v, 2, 16));
      v = fmaxf(v, __shfl_xor(v, 4, 16));
      v = fmaxf(v, __shfl_xor(v, 8, 16));
      const float mn = fmaxf(m_i[r], v);
      alpha[r] = exp2f((m_i[r] - mn) * LOG2E);
      m_i[r] = mn;
    }
#pragma unroll
    for (int r = 0; r < 4; ++r) {
      const float p0 = exp2f((s[0][r] - m_i[r]) * LOG2E);
      const float p1 = exp2f((s[1][r] - m_i[r]) * LOG2E);
      s[0][r] = p0; s[1][r] = p1;
      float v = p0 + p1;
      v += __shfl_xor(v, 1, 16);
      v += __shfl_xor(v, 2, 16);
      v += __shfl_xor(v, 4, 16);
      v += __shfl_xor(v, 8, 16);
      l_i[r] = l_i[r] * alpha[r] + v;
    }
#pragma unroll
    for (int t = 0; t < 4; ++t)
#pragma unroll
      for (int r = 0; r < 4; ++r) o[t][r] *= alpha[r];

    // P: C-layout -> LDS -> A-operand layout (verified m120 transform)
#pragma unroll
    for (int kt = 0; kt < 2; ++kt)
#pragma unroll
      for (int r = 0; r < 4; ++r)
        Pw[(quad * 4 + r) * 32 + kt * 16 + l15] = f2bf(s[kt][r]);
    __syncthreads();   // ordering fence (uniform across waves)

    bfrag pf = *(const bfrag*)(Pw + l15 * 32 + quad * 8);
    // O += P V ; V^T rows give contiguous B-operand frags
#pragma unroll
    for (int t = 0; t < 4; ++t) {
      bfrag vf = *(const bfrag*)(Vt + baseN + (((long)(t * 16 + l15)) << 11) + k0 + quad * 8);
      o[t] = __builtin_amdgcn_mfma_f32_16x16x32_bf16(pf, vf, o[t], 0, 0, 0);
    }
    __syncthreads();   // keep next-iter P writes behind this iter's reads
  }

  // epilogue: O/l -> [B, N, H*D] (bf16 intermediate)
#pragma unroll
  for (int r = 0; r < 4; ++r) l_i[r] = 1.0f / l_i[r];
#pragma unroll
  for (int t = 0; t < 4; ++t)
#pragma unroll
    for (int r = 0; r < 4; ++r) {
      const int row = q0 + quad * 4 + r;
      AO[(((long)(b * 2048 + row)) << 10) + h * 64 + t * 16 + l15] = f2bf(o[t][r] * l_i[r]);
    }
}

// Kernel 3: out = AO @ proj_w^T + proj_b  (f32 output)
__global__ __launch_bounds__(256) void proj_kernel(
    const u16* __restrict__ Ain, const u16* __restrict__ w,
    const float* __restrict__ pb, float* __restrict__ out)
{
  __shared__ u16 As[128 * 32];
  __shared__ u16 Bs[128 * 32];
  facc acc[4][4];
  const int m0 = blockIdx.y * 128;
  const int n0 = blockIdx.x * 128;
  gemm128_bt(Ain, w, 1024, m0, n0, As, Bs, acc);

  const int lane = threadIdx.x & 63;
  const int wv = threadIdx.x >> 6;
  const int quad = lane >> 4, l15 = lane & 15;
  const int wm = wv >> 1, wn = wv & 1;
#pragma unroll
  for (int j = 0; j < 4; ++j) {
    const int n_g = n0 + wn * 64 + j * 16 + l15;
    const float pbv = pb[n_g];
#pragma unroll
    for (int i = 0; i < 4; ++i) {
      const int mg0 = m0 + wm * 64 + i * 16 + quad * 4;
#pragma unroll
      for (int r = 0; r < 4; ++r)
        out[(((long)(mg0 + r)) << 10) + n_g] = acc[i][j][r] + pbv;
    }
  }
}

extern "C" void kernel_launch(void* const* d_in, const int* in_sizes, int n_in,
                              void* d_out, int out_size, void* d_ws, size_t ws_size,
                              hipStream_t stream)
{
  const float* x    = (const float*)d_in[0];   // [2,2048,1024] f32
  const float* bias = (const float*)d_in[1];   // [16,2048,2048] f32
  const float* qkvw = (const float*)d_in[2];   // [3072,1024] f32
  const float* qb   = (const float*)d_in[3];   // [1024] f32
  const float* vb   = (const float*)d_in[4];   // [1024] f32
  const float* pw   = (const float*)d_in[5];   // [1024,1024] f32
  const float* pb   = (const float*)d_in[6];   // [1024] f32
  float* out = (float*)d_out;                  // [2,2048,1024] f32

  char* ws = (char*)d_ws;                      // 48 MiB used
  u16* Q    = (u16*)(ws);                                  // [B,H,N,D]  8 MiB
  u16* Kd   = (u16*)(ws + (size_t)8  * 1024 * 1024);       // [B,H,N,D]  8 MiB
  u16* Vt   = (u16*)(ws + (size_t)16 * 1024 * 1024);       // [B,H,D,N]  8 MiB
  u16* AO   = (u16*)(ws + (size_t)24 * 1024 * 1024);       // [B,N,C]    8 MiB
  u16* xb   = (u16*)(ws + (size_t)32 * 1024 * 1024);       // x bf16     8 MiB
  u16* qwb  = (u16*)(ws + (size_t)40 * 1024 * 1024);       // qkv_w bf16 6 MiB
  u16* pwb  = (u16*)(ws + (size_t)46 * 1024 * 1024);       // proj_w bf16 2 MiB

  hipLaunchKernelGGL(convert_kernel, dim3(1024), dim3(256), 0, stream,
                     x, qkvw, pw, xb, qwb, pwb);
  hipLaunchKernelGGL(qkv_gemm_kernel, dim3(24, 32), dim3(256), 0, stream,
                     xb, qwb, qb, vb, Q, Kd, Vt);
  hipLaunchKernelGGL(attn_kernel, dim3(1024), dim3(256), 0, stream,
                     Q, Kd, Vt, bias, AO);
  hipLaunchKernelGGL(proj_kernel, dim3(8, 32), dim3(256), 0, stream,
                     AO, pwb, pb, out);
}